// Round 2
// baseline (237.194 us; speedup 1.0000x reference)
//
#include <hip/hip_runtime.h>
#include <hip/hip_bf16.h>

#define NQ 4096
#define NS 16384
#define DIM 128
#define NC 64
#define INFV 1000.0f

using bf16 = __hip_bfloat16;
typedef __attribute__((ext_vector_type(8))) short frag_ab;   // 8 bf16 = 4 VGPRs
typedef __attribute__((ext_vector_type(4))) float frag_cd;   // 4 fp32 acc

// ---------------------------------------------------------------- init
__global__ void k_init(float* __restrict__ summed, float* __restrict__ mus,
                       float* __restrict__ csum, int* __restrict__ counts,
                       float* __restrict__ out) {
    int gid = blockIdx.x * blockDim.x + threadIdx.x;
    int stride = gridDim.x * blockDim.x;
    for (int i = gid; i < NQ * NC; i += stride) summed[i] = 0.f;
    for (int i = gid; i < NC * DIM; i += stride) mus[i] = 0.f;
    if (gid < NC) { csum[gid] = 0.f; counts[gid] = 0; }
    if (gid == 0) out[0] = 0.f;
}

// ---------------------------------------------------------------- class histogram
__global__ void k_hist(const int* __restrict__ ys, int* __restrict__ counts) {
    int j = blockIdx.x * 256 + threadIdx.x;
    if (j < NS) atomicAdd(&counts[ys[j]], 1);
}

// ---------------------------------------------------------------- exclusive scan (C=64, 1 wave)
__global__ void k_scan(const int* __restrict__ counts, int* __restrict__ cursor,
                       int* __restrict__ offsets) {
    int t = threadIdx.x;  // 0..63
    int off = 0;
    for (int c = 0; c < t; ++c) off += counts[c];
    cursor[t] = off;
    offsets[t] = off;
}

// ---------------------------------------------------------------- scatter support indices by class
__global__ void k_scatter(const int* __restrict__ ys, int* __restrict__ cursor,
                          int* __restrict__ order, int* __restrict__ ysrt) {
    int j = blockIdx.x * 256 + threadIdx.x;
    if (j < NS) {
        int c = ys[j];
        int r = atomicAdd(&cursor[c], 1);
        order[r] = j;
        ysrt[r] = c;
    }
}

// ---------------------------------------------------------------- prep: bf16 cast/gather + sqq + mus/csum
// blocks [0, (NS+NQ)/4): one wave per row (sorted xs then xq), cast + query norms
// blocks [(NS+NQ)/4, +NC*4): per-class prototype sums (fp32) + class sq-norm sums
__global__ __launch_bounds__(256) void k_prep(
    const float* __restrict__ xs, const float* __restrict__ xq,
    const int* __restrict__ order, const int* __restrict__ offsets,
    const int* __restrict__ counts,
    bf16* __restrict__ xsb, bf16* __restrict__ xqb,
    float* __restrict__ sqq, float* __restrict__ mus, float* __restrict__ csum) {
    const int ROWB = (NS + NQ) / 4;
    int b = blockIdx.x;
    if (b < ROWB) {
        int wave = threadIdx.x >> 6, lane = threadIdx.x & 63;
        int row = b * 4 + wave;
        const float* src;
        bf16* dst;
        bool isq = row >= NS;
        if (!isq) {
            int s = order[row];
            src = xs + (size_t)s * DIM;
            dst = xsb + (size_t)row * DIM;
        } else {
            int r2 = row - NS;
            src = xq + (size_t)r2 * DIM;
            dst = xqb + (size_t)r2 * DIM;
        }
        float2 v = *(const float2*)(src + lane * 2);
        __hip_bfloat162 h2;
        h2.x = __float2bfloat16(v.x);
        h2.y = __float2bfloat16(v.y);
        *(__hip_bfloat162*)(dst + lane * 2) = h2;
        if (isq) {
            float sq = v.x * v.x + v.y * v.y;
#pragma unroll
            for (int m = 1; m < 64; m <<= 1) sq += __shfl_xor(sq, m, 64);
            if (lane == 0) sqq[row - NS] = sq;
        }
    } else {
        int mb = b - ROWB;            // 0..NC*4-1
        int c = mb >> 2, qtr = mb & 3;
        int o = offsets[c], n = counts[c];
        int d = threadIdx.x & 127, half = threadIdx.x >> 7;
        float s = 0.f, s2 = 0.f;
#pragma unroll 4
        for (int i = 0; i < 32; ++i) {
            int r = qtr * 64 + half * 32 + i;
            if (r < n) {
                int srcr = order[o + r];
                float x = xs[(size_t)srcr * DIM + d];
                s += x;
                s2 += x * x;
            }
        }
        atomicAdd(&mus[c * DIM + d], s);
#pragma unroll
        for (int m = 1; m < 64; m <<= 1) s2 += __shfl_xor(s2, m, 64);
        if ((threadIdx.x & 63) == 0) atomicAdd(&csum[c], s2);
    }
}

// ---------------------------------------------------------------- main: pure-MFMA class-dot sums
// grid (NQ/128, NS/512) x 256 threads (4 waves). Wave owns 32 queries (2 A-sets).
// B-frags loaded straight from global (sorted xsb) -> no LDS, no barriers.
// MFMA C-operand accumulates Sum_j dot(q, s_j) across an entire class run
// (valid: we only ever need the row-sum over j; relu dropped since pair
// distances are >> bf16 noise and the pos diagonal is replaced in k_final).
// Assumes class runs are 16-aligned and don't straddle 512-row slices
// (guaranteed here: 256 rows/class, 256-aligned offsets).
__global__ __launch_bounds__(256) void k_main(
    const bf16* __restrict__ xqb, const bf16* __restrict__ xsb,
    const float* __restrict__ sqq, const float* __restrict__ csum,
    const int* __restrict__ counts, const int* __restrict__ ysrt,
    float* __restrict__ summed) {
    const int tid = threadIdx.x;
    const int wave = tid >> 6, lane = tid & 63;
    const int quad = lane >> 4, l15 = lane & 15;
    const int qbase = blockIdx.x * 128 + wave * 32;
    const int jbase = blockIdx.y * 512;

    frag_ab afr[2][4];
#pragma unroll
    for (int s = 0; s < 2; ++s) {
        const short* src = (const short*)xqb + (size_t)(qbase + s * 16 + l15) * DIM + quad * 8;
#pragma unroll
        for (int kk = 0; kk < 4; ++kk) afr[s][kk] = *(const frag_ab*)(src + kk * 32);
    }
    float sqq_r[2][4];
#pragma unroll
    for (int s = 0; s < 2; ++s)
#pragma unroll
        for (int r = 0; r < 4; ++r) sqq_r[s][r] = sqq[qbase + s * 16 + quad * 4 + r];

    frag_cd acc[2][2];
#pragma unroll
    for (int s = 0; s < 2; ++s)
#pragma unroll
        for (int p = 0; p < 2; ++p)
#pragma unroll
            for (int e = 0; e < 4; ++e) acc[s][p][e] = 0.f;

    int cur_cls = ysrt[jbase];

    auto flush = [&]() {
        float cnt = (float)counts[cur_cls];
        float sc = csum[cur_cls];
#pragma unroll
        for (int s = 0; s < 2; ++s) {
#pragma unroll
            for (int r = 0; r < 4; ++r) {
                float v = acc[s][0][r] + acc[s][1][r];
                v += __shfl_xor(v, 1, 64);
                v += __shfl_xor(v, 2, 64);
                v += __shfl_xor(v, 4, 64);
                v += __shfl_xor(v, 8, 64);
                if (l15 == 0) {
                    int q = qbase + s * 16 + quad * 4 + r;
                    float total = cnt * sqq_r[s][r] + sc - 2.f * v;
                    atomicAdd(&summed[(size_t)q * NC + cur_cls], -0.5f * total);
                }
            }
#pragma unroll
            for (int p = 0; p < 2; ++p)
#pragma unroll
                for (int e = 0; e < 4; ++e) acc[s][p][e] = 0.f;
        }
    };

    for (int ct = 0; ct < 32; ++ct) {
        const int j0 = jbase + ct * 16;
        int cls = ysrt[j0];
        if (cls != cur_cls) {  // rare, wave-uniform
            flush();
            cur_cls = cls;
        }
        const short* bb = (const short*)xsb + (size_t)(j0 + l15) * DIM + quad * 8;
        frag_ab bfr[4];
#pragma unroll
        for (int kk = 0; kk < 4; ++kk) bfr[kk] = *(const frag_ab*)(bb + kk * 32);
#pragma unroll
        for (int kk = 0; kk < 4; ++kk) {
            acc[0][kk & 1] =
                __builtin_amdgcn_mfma_f32_16x16x32_bf16(afr[0][kk], bfr[kk], acc[0][kk & 1], 0, 0, 0);
            acc[1][kk & 1] =
                __builtin_amdgcn_mfma_f32_16x16x32_bf16(afr[1][kk], bfr[kk], acc[1][kk & 1], 0, 0, 0);
        }
    }
    flush();
}

// ---------------------------------------------------------------- per-query pos fixup + logsumexp + mean
__global__ __launch_bounds__(256) void k_final(
    const float* __restrict__ xq, const int* __restrict__ yq,
    const float* __restrict__ xs, const int* __restrict__ ys,
    const int* __restrict__ pos, const int* __restrict__ counts,
    const float* __restrict__ mus, const float* __restrict__ summed,
    float* __restrict__ out) {
    __shared__ float red[4];
    int wave = threadIdx.x >> 6, lane = threadIdx.x & 63;
    int i = blockIdx.x * 4 + wave;  // NQ % 4 == 0, always valid
    int pi = pos[i];
    int yqi = yq[i];
    int cp = ys[pi];
    float cnt_p = (float)counts[cp];
    float cnt_yq = (float)counts[yqi];
    bool idx = cnt_yq > 1.f;
    float denom = fmaxf(cnt_p - 1.f, 0.1f);

    float2 q2 = *(const float2*)(xq + (size_t)i * DIM + lane * 2);
    float2 s2 = *(const float2*)(xs + (size_t)pi * DIM + lane * 2);
    float2 m2 = *(const float2*)(mus + (size_t)cp * DIM + lane * 2);

    float dot = q2.x * s2.x + q2.y * s2.y;
    float sqn_q = q2.x * q2.x + q2.y * q2.y;
    float sqn_s = s2.x * s2.x + s2.y * s2.y;
    float px = (m2.x - q2.x) / denom, py = (m2.y - q2.y) / denom;
    float dx = q2.x - px, dy = q2.y - py;
    float dd = dx * dx + dy * dy;
#pragma unroll
    for (int m = 1; m < 64; m <<= 1) {
        dot += __shfl_xor(dot, m, 64);
        sqn_q += __shfl_xor(sqn_q, m, 64);
        sqn_s += __shfl_xor(sqn_s, m, 64);
        dd += __shfl_xor(dd, m, 64);
    }
    float pos_logit = -sqrtf(fmaxf(dd, 0.f));
    float logit_pos = -0.5f * fmaxf(sqn_q + sqn_s - 2.f * dot, 0.f);
    float corr = (idx ? -INFV : 0.f) - logit_pos;  // replace pos entry's contribution

    // lane = class (NC == 64)
    float v = summed[(size_t)i * NC + lane];
    if (lane == cp) v += corr;
    float cnt_c = (float)counts[lane];
    v = v / (cnt_c - 1.f);
    float mx = v;
#pragma unroll
    for (int m = 1; m < 64; m <<= 1) mx = fmaxf(mx, __shfl_xor(mx, m, 64));
    float e = __expf(v - mx);
#pragma unroll
    for (int m = 1; m < 64; m <<= 1) e += __shfl_xor(e, m, 64);
    float neg = mx + __logf(e);
    if (lane == 0) red[wave] = neg - pos_logit;
    __syncthreads();
    if (threadIdx.x == 0)
        atomicAdd(out, (red[0] + red[1] + red[2] + red[3]) * (1.f / NQ));
}

// ---------------------------------------------------------------- launcher
extern "C" void kernel_launch(void* const* d_in, const int* in_sizes, int n_in,
                              void* d_out, int out_size, void* d_ws, size_t ws_size,
                              hipStream_t stream) {
    const float* xq = (const float*)d_in[0];
    const int* yq = (const int*)d_in[1];
    const float* xs = (const float*)d_in[2];
    const int* ys = (const int*)d_in[3];
    const int* pos = (const int*)d_in[4];
    float* out = (float*)d_out;

    char* w = (char*)d_ws;
    float* summed = (float*)w;  w += (size_t)NQ * NC * 4;   // 1 MB
    float* mus    = (float*)w;  w += (size_t)NC * DIM * 4;  // 32 KB
    float* csum   = (float*)w;  w += 256 * 4;
    int* counts   = (int*)w;    w += 256;
    int* cursor   = (int*)w;    w += 256;
    int* offsets  = (int*)w;    w += 256;
    int* order    = (int*)w;    w += (size_t)NS * 4;        // 64 KB
    int* ysrt     = (int*)w;    w += (size_t)NS * 4;        // 64 KB
    bf16* xsb     = (bf16*)w;   w += (size_t)NS * DIM * 2;  // 4 MB (sorted)
    bf16* xqb     = (bf16*)w;   w += (size_t)NQ * DIM * 2;  // 1 MB
    float* sqq    = (float*)w;  w += (size_t)NQ * 4;

    k_init<<<256, 256, 0, stream>>>(summed, mus, csum, counts, out);
    k_hist<<<NS / 256, 256, 0, stream>>>(ys, counts);
    k_scan<<<1, 64, 0, stream>>>(counts, cursor, offsets);
    k_scatter<<<NS / 256, 256, 0, stream>>>(ys, cursor, order, ysrt);
    k_prep<<<(NS + NQ) / 4 + NC * 4, 256, 0, stream>>>(xs, xq, order, offsets, counts,
                                                        xsb, xqb, sqq, mus, csum);
    k_main<<<dim3(NQ / 128, NS / 512), 256, 0, stream>>>(xqb, xsb, sqq, csum, counts,
                                                          ysrt, summed);
    k_final<<<NQ / 4, 256, 0, stream>>>(xq, yq, xs, ys, pos, counts, mus, summed, out);
}

// Round 3
// 113.610 us; speedup vs baseline: 2.0878x; 2.0878x over previous
//
#include <hip/hip_runtime.h>
#include <hip/hip_bf16.h>

#define NQ 4096
#define NS 16384
#define DIM 128
#define NC 64
#define INFV 1000.0f

using bf16 = __hip_bfloat16;
typedef __attribute__((ext_vector_type(8))) short frag_ab;   // 8 bf16 = 4 VGPRs
typedef __attribute__((ext_vector_type(4))) float frag_cd;   // 4 fp32 acc

__device__ inline frag_ab pack8(float4 a, float4 b) {
    union { __hip_bfloat16 h; short s; } u;
    frag_ab f;
    u.h = __float2bfloat16(a.x); f[0] = u.s;
    u.h = __float2bfloat16(a.y); f[1] = u.s;
    u.h = __float2bfloat16(a.z); f[2] = u.s;
    u.h = __float2bfloat16(a.w); f[3] = u.s;
    u.h = __float2bfloat16(b.x); f[4] = u.s;
    u.h = __float2bfloat16(b.y); f[5] = u.s;
    u.h = __float2bfloat16(b.z); f[6] = u.s;
    u.h = __float2bfloat16(b.w); f[7] = u.s;
    return f;
}

// ---------------------------------------------------------------- k1: class stats
// grid 128 blocks (c = b>>1, half = b&1) x 128 threads (2 waves).
// Each wave scans NS/4 = 4096 support labels with ballot; matched rows are
// accumulated (prototype sum + sq-norm sum + count) into DISJOINT partial
// slot s = half*2+wave. No atomics, no zero-init required.
__global__ __launch_bounds__(128) void k1_stats(
    const float* __restrict__ xs, const int* __restrict__ ys,
    float* __restrict__ mus_p, float* __restrict__ csum_p,
    int* __restrict__ counts_p) {
    const int c = blockIdx.x >> 1, half = blockIdx.x & 1;
    const int w = threadIdx.x >> 6, lane = threadIdx.x & 63;
    const int s = half * 2 + w;          // slot 0..3
    const int base = s * (NS / 4);       // 4096-row segment
    const float2* xs2 = (const float2*)xs;

    float2 macc = {0.f, 0.f};
    float sacc = 0.f;
    int cnt = 0;
    for (int i = 0; i < NS / 4; i += 64) {
        int y = ys[base + i + lane];
        unsigned long long m = __ballot(y == c);
        cnt += (int)__popcll(m);
        while (m) {                       // wave-uniform loop, ~1 match/chunk
            int b = __ffsll((long long)m) - 1;
            m &= m - 1;
            int row = base + i + b;
            float2 v = xs2[(size_t)row * 64 + lane];
            macc.x += v.x; macc.y += v.y;
            sacc += v.x * v.x + v.y * v.y;
        }
    }
    ((float2*)mus_p)[(size_t)(c * 4 + s) * 64 + lane] = macc;
#pragma unroll
    for (int mm = 1; mm < 64; mm <<= 1) sacc += __shfl_xor(sacc, mm, 64);
    if (lane == 0) {
        csum_p[c * 4 + s] = sacc;
        counts_p[c * 4 + s] = cnt;
    }
}

// ---------------------------------------------------------------- k2: everything else
// grid 64 blocks x 256 threads; block owns 64 queries (16/wave).
// Phase 0: reduce S=4 partials -> mus/cnt/csum in LDS (132-float padded rows).
// Phase 1: per-query fp32 scalars (sqq, exact pos-entry logit, proto pos_logit).
// Phase 2: 16x16x32 bf16 MFMA: [16q x 128] x [128 x 64c] dots.
// Phase 3: summed -> normalized (+pos corr) -> logsumexp -> mean (atomicAdd out).
__global__ __launch_bounds__(256) void k2_main(
    const float* __restrict__ xq, const int* __restrict__ yq,
    const float* __restrict__ xs, const int* __restrict__ ys,
    const int* __restrict__ pos,
    const float* __restrict__ mus_p, const float* __restrict__ csum_p,
    const int* __restrict__ counts_p, float* __restrict__ out) {
    __shared__ float mus_lds[64 * 132];   // +4 pad: ds_read_b128 2-way only
    __shared__ float cnt_lds[64];
    __shared__ float csum_lds[64];
    __shared__ float sqq_a[64], corr_a[64], pospl_a[64];
    __shared__ int cp_a[64];
    __shared__ float red[4];

    const int tid = threadIdx.x, w = tid >> 6, lane = tid & 63;
    const int quad = lane >> 4, l15 = lane & 15;
    const int qbase = blockIdx.x * 64 + w * 16;

    // ---- phase 0: partial reduction into LDS
#pragma unroll 4
    for (int r = 0; r < 32; ++r) {
        int i = r * 256 + tid;            // flat (c,d)
        int c = i >> 7, d = i & 127;
        float ssum = 0.f;
#pragma unroll
        for (int s = 0; s < 4; ++s) ssum += mus_p[(size_t)(c * 4 + s) * 128 + d];
        mus_lds[c * 132 + d] = ssum;
    }
    if (tid < 64) {
        float cs = 0.f; int cc = 0;
#pragma unroll
        for (int s = 0; s < 4; ++s) { cs += csum_p[tid * 4 + s]; cc += counts_p[tid * 4 + s]; }
        csum_lds[tid] = cs;
        cnt_lds[tid] = (float)cc;
    }
    __syncthreads();

    // ---- phase 1: per-query scalars (lane = q_loc*4 + chunk, 32 dims/lane)
    {
        int q_loc = lane >> 2, chunk = lane & 3;
        int q = qbase + q_loc;
        int pi = pos[q];
        int yqi = yq[q];
        int cp = ys[pi];
        float cnt_p = cnt_lds[cp];
        float inv_d = 1.f / fmaxf(cnt_p - 1.f, 0.1f);
        bool idxq = cnt_lds[yqi] > 1.f;
        float sqq = 0.f, dotv = 0.f, sqs = 0.f, dd = 0.f;
#pragma unroll
        for (int t = 0; t < 8; ++t) {
            int d0 = chunk * 32 + t * 4;
            float4 a = *(const float4*)(xq + (size_t)q * DIM + d0);
            float4 b = *(const float4*)(xs + (size_t)pi * DIM + d0);
            float4 m = *(const float4*)(&mus_lds[cp * 132 + d0]);
            sqq += a.x * a.x + a.y * a.y + a.z * a.z + a.w * a.w;
            dotv += a.x * b.x + a.y * b.y + a.z * b.z + a.w * b.w;
            sqs += b.x * b.x + b.y * b.y + b.z * b.z + b.w * b.w;
            float ex;
            ex = a.x - (m.x - a.x) * inv_d; dd += ex * ex;
            ex = a.y - (m.y - a.y) * inv_d; dd += ex * ex;
            ex = a.z - (m.z - a.z) * inv_d; dd += ex * ex;
            ex = a.w - (m.w - a.w) * inv_d; dd += ex * ex;
        }
#pragma unroll
        for (int mm = 1; mm < 4; mm <<= 1) {
            sqq += __shfl_xor(sqq, mm, 64);
            dotv += __shfl_xor(dotv, mm, 64);
            sqs += __shfl_xor(sqs, mm, 64);
            dd += __shfl_xor(dd, mm, 64);
        }
        if (chunk == 0) {
            float raw = -0.5f * fmaxf(sqq + sqs - 2.f * dotv, 0.f);
            sqq_a[w * 16 + q_loc] = sqq;
            corr_a[w * 16 + q_loc] = (idxq ? -INFV : 0.f) - raw;
            pospl_a[w * 16 + q_loc] = -sqrtf(fmaxf(dd, 0.f));
            cp_a[w * 16 + q_loc] = cp;
        }
    }
    __syncthreads();

    // ---- phase 2: MFMA dot(q, mus_c)  (A: 16 queries, B: 64 classes)
    frag_ab afr[4];
    {
        const float* src0 = xq + (size_t)(qbase + l15) * DIM + quad * 8;
#pragma unroll
        for (int kk = 0; kk < 4; ++kk) {
            const float* s = src0 + kk * 32;
            afr[kk] = pack8(*(const float4*)s, *(const float4*)(s + 4));
        }
    }
    frag_cd acc[4];
#pragma unroll
    for (int ct = 0; ct < 4; ++ct) {
#pragma unroll
        for (int e = 0; e < 4; ++e) acc[ct][e] = 0.f;
        const float* bsrc = &mus_lds[(ct * 16 + l15) * 132 + quad * 8];
        frag_ab bfr[4];
#pragma unroll
        for (int kk = 0; kk < 4; ++kk) {
            const float* s = bsrc + kk * 32;
            bfr[kk] = pack8(*(const float4*)s, *(const float4*)(s + 4));
        }
#pragma unroll
        for (int kk = 0; kk < 4; ++kk)
            acc[ct] = __builtin_amdgcn_mfma_f32_16x16x32_bf16(afr[kk], bfr[kk], acc[ct], 0, 0, 0);
    }

    // ---- phase 3: normalized + pos corr + logsumexp + mean
    float norm[4][4];
#pragma unroll
    for (int ct = 0; ct < 4; ++ct) {
        int cB = ct * 16 + l15;
        float cc = cnt_lds[cB], cs = csum_lds[cB];
        float invc = 1.f / (cc - 1.f);
#pragma unroll
        for (int r = 0; r < 4; ++r) {
            int q_loc = quad * 4 + r;
            float sv = -0.5f * (cc * sqq_a[w * 16 + q_loc] + cs - 2.f * acc[ct][r]);
            if (cB == cp_a[w * 16 + q_loc]) sv += corr_a[w * 16 + q_loc];
            norm[ct][r] = sv * invc;
        }
    }
    float tacc = 0.f;
#pragma unroll
    for (int r = 0; r < 4; ++r) {
        float mx = fmaxf(fmaxf(norm[0][r], norm[1][r]), fmaxf(norm[2][r], norm[3][r]));
#pragma unroll
        for (int mm = 1; mm < 16; mm <<= 1) mx = fmaxf(mx, __shfl_xor(mx, mm, 64));
        float e = expf(norm[0][r] - mx) + expf(norm[1][r] - mx) +
                  expf(norm[2][r] - mx) + expf(norm[3][r] - mx);
#pragma unroll
        for (int mm = 1; mm < 16; mm <<= 1) e += __shfl_xor(e, mm, 64);
        float lse = mx + logf(e);
        tacc += lse - pospl_a[w * 16 + quad * 4 + r];
    }
    tacc = (l15 == 0) ? tacc : 0.f;
#pragma unroll
    for (int mm = 1; mm < 64; mm <<= 1) tacc += __shfl_xor(tacc, mm, 64);
    if (lane == 0) red[w] = tacc;
    __syncthreads();
    if (tid == 0)
        atomicAdd(out, (red[0] + red[1] + red[2] + red[3]) * (1.f / NQ));
}

// ---------------------------------------------------------------- launcher
extern "C" void kernel_launch(void* const* d_in, const int* in_sizes, int n_in,
                              void* d_out, int out_size, void* d_ws, size_t ws_size,
                              hipStream_t stream) {
    const float* xq = (const float*)d_in[0];
    const int* yq = (const int*)d_in[1];
    const float* xs = (const float*)d_in[2];
    const int* ys = (const int*)d_in[3];
    const int* pos = (const int*)d_in[4];
    float* out = (float*)d_out;

    char* wsp = (char*)d_ws;
    float* mus_p   = (float*)wsp; wsp += (size_t)NC * 4 * DIM * 4;  // 128 KB
    float* csum_p  = (float*)wsp; wsp += NC * 4 * 4;                // 1 KB
    int* counts_p  = (int*)wsp;   wsp += NC * 4 * 4;                // 1 KB

    hipMemsetAsync(out, 0, sizeof(float), stream);
    k1_stats<<<NC * 2, 128, 0, stream>>>(xs, ys, mus_p, csum_p, counts_p);
    k2_main<<<NQ / 64, 256, 0, stream>>>(xq, yq, xs, ys, pos,
                                         mus_p, csum_p, counts_p, out);
}